// Round 14
// baseline (200.577 us; speedup 1.0000x reference)
//
#include <hip/hip_runtime.h>
#include <hip/hip_bf16.h>
#include <hip/hip_fp16.h>
#include <math.h>

// Problem constants
#define BB 8
#define CC 256
#define HH 64
#define WW 64
#define GG 16
#define GCH 16
#define PP 9
#define NPIX (BB*HH*WW)   // 32768

typedef __attribute__((ext_vector_type(4))) float f32x4;
typedef __attribute__((ext_vector_type(2))) float f32x2;
typedef __bf16 bf16x8 __attribute__((ext_vector_type(8)));

#define GLOAD_LDS16(g, l) __builtin_amdgcn_global_load_lds( \
    (const __attribute__((address_space(1))) unsigned int*)(g), \
    (__attribute__((address_space(3))) unsigned int*)(l), 16, 0, 0)

// unpack a u32 holding 2 bf16 -> 2 floats (elem0 = low 16 bits)
__device__ __forceinline__ void bfu2(unsigned a, float& lo, float& hi) {
    union { unsigned u; float f; } t0, t1;
    t0.u = a << 16; t1.u = a & 0xffff0000u;
    lo = t0.f; hi = t1.f;
}
__device__ __forceinline__ f32x2 bfup2(unsigned a) {
    union { unsigned u; float f; } t0, t1;
    t0.u = a << 16; t1.u = a & 0xffff0000u;
    return (f32x2){t0.f, t1.f};
}

// ---------------------------------------------------------------------------
// K0: merged weight prep.
__global__ void prep_kernel(const float* __restrict__ inw, const float* __restrict__ offw,
                            const float* __restrict__ mskw, const float* __restrict__ outpw,
                            const float* __restrict__ pww, const float* __restrict__ outpb,
                            const float* __restrict__ pwb, const float* __restrict__ offb,
                            const float* __restrict__ mskb,
                            __hip_bfloat16* __restrict__ bt_in, __hip_bfloat16* __restrict__ bt_om,
                            __hip_bfloat16* __restrict__ bt_wc, float* __restrict__ bcomb,
                            float* __restrict__ bcat) {
    __shared__ float pd[256];
    int bid = blockIdx.x;
    int t = threadIdx.x;
    if (bid < 256) {
        bt_in[bid * 256 + t] = __float2bfloat16(inw[t * 256 + bid]);
    } else if (bid < 704) {
        int n = bid - 256;    // 0..447
        float v = 0.0f;
        if (n < 288)      v = offw[t * 288 + n];
        else if (n < 432) v = mskw[t * 144 + (n - 288)];
        bt_om[(size_t)n * 256 + t] = __float2bfloat16(v);
    } else if (bid < 960) {
        int d = bid - 704;
        pd[t] = pww[d * 256 + t];
        __syncthreads();
        const float* ow = outpw + t * 256;
        float s = 0.0f;
        #pragma unroll 8
        for (int c = 0; c < 256; ++c) s += ow[c] * pd[c];
        bt_wc[d * 256 + t] = __float2bfloat16(s);
    } else if (bid == 960) {
        const float* pr = pww + t * 256;
        float s = pwb[t];
        #pragma unroll 8
        for (int c = 0; c < 256; ++c) s += outpb[c] * pr[c];
        bcomb[t] = s;
    } else {
        int i = (bid - 961) * 256 + t;    // 0..511
        if (i < 448) bcat[i] = (i < 288) ? offb[i] : (i < 432 ? mskb[i - 288] : 0.0f);
    }
}

// ---------------------------------------------------------------------------
// K1 v4: 5x5 depthwise conv, pad 2. x: NCHW fp32 -> out NHWC bf16 ONLY.
#define C0PLANE 817   // 12*68 + 1
__global__ void conv0_kernel(const float* __restrict__ x, const float* __restrict__ w,
                             const float* __restrict__ b,
                             __hip_bfloat16* __restrict__ out_bf) {
    __shared__ float sx[16 * C0PLANE];   // 52288 B
    int t  = threadIdx.x;
    int st = blockIdx.x;                 // row strip 0..7
    int cg = blockIdx.y;                 // channel group
    int n  = blockIdx.z;
    int h0 = st * 8;
    int c0 = cg * 16;

    #pragma unroll
    for (int i = 0; i < 12; ++i) {
        int task = i * 256 + t;
        int lane = task & 15;
        int pair = task >> 4;
        int c    = pair / 12;
        int row  = pair - c * 12;
        int gy   = h0 - 2 + row;
        float4 v = make_float4(0.f, 0.f, 0.f, 0.f);
        if (gy >= 0 && gy < HH)
            v = *(const float4*)(x + (((size_t)(n * CC + c0 + c)) * HH + gy) * WW + lane * 4);
        *(float4*)&sx[c * C0PLANE + row * 68 + 2 + lane * 4] = v;
    }
    if (t < 192) {
        int c = t / 12, row = t - (t / 12) * 12;
        float* p = &sx[c * C0PLANE + row * 68];
        p[0] = 0.f; p[1] = 0.f; p[66] = 0.f; p[67] = 0.f;
    }
    __syncthreads();

    int c = t & 15;
    int s = t >> 4;
    float wreg[25];
    const float* wp = w + (c0 + c) * 25;
    #pragma unroll
    for (int i = 0; i < 25; ++i) wreg[i] = wp[i];
    float bias = b[c0 + c];
    const float* cp = &sx[c * C0PLANE + s * 4];

    float win[5][8];
    #pragma unroll
    for (int rr = 0; rr < 4; ++rr)
        #pragma unroll
        for (int j = 0; j < 8; ++j) win[rr][j] = cp[rr * 68 + j];

    #pragma unroll
    for (int r = 0; r < 8; ++r) {
        #pragma unroll
        for (int j = 0; j < 8; ++j) win[(r + 4) % 5][j] = cp[(r + 4) * 68 + j];
        float a0 = bias, a1 = bias, a2 = bias, a3 = bias;
        #pragma unroll
        for (int dy = 0; dy < 5; ++dy) {
            const float* wr = &wreg[dy * 5];
            const float* wd = win[(r + dy) % 5];
            #pragma unroll
            for (int dx = 0; dx < 5; ++dx) {
                float wv = wr[dx];
                a0 += wd[0 + dx] * wv;
                a1 += wd[1 + dx] * wv;
                a2 += wd[2 + dx] * wv;
                a3 += wd[3 + dx] * wv;
            }
        }
        size_t pixb = ((size_t)n * 4096 + (h0 + r) * 64 + s * 4) << 8;
        out_bf[pixb + c0 + c]       = __float2bfloat16(a0);
        out_bf[pixb + 256 + c0 + c] = __float2bfloat16(a1);
        out_bf[pixb + 512 + c0 + c] = __float2bfloat16(a2);
        out_bf[pixb + 768 + c0 + c] = __float2bfloat16(a3);
    }
}

// ---------------------------------------------------------------------------
// K2 v3: 3x3 depthwise conv on bf16 NHWC + LayerNorm(C) + exact GELU -> x1 (bf16)
__global__ void dwln_kernel(const __hip_bfloat16* __restrict__ inp, const float* __restrict__ dww,
                            const float* __restrict__ dwb, const float* __restrict__ lng,
                            const float* __restrict__ lnb, __hip_bfloat16* __restrict__ x1) {
    __shared__ float sx[3 * 10 * 256];   // 30720 B
    __shared__ float ls1[8][4], ls2[8][4];
    int t  = threadIdx.x;
    int x0 = blockIdx.x * 8;
    int h  = blockIdx.y;
    int n  = blockIdx.z;

    #pragma unroll
    for (int i = 0; i < 4; ++i) {
        int task = i * 256 + t;          // 0..1023, need 960
        if (task < 960) {
            int c8  = task & 31;
            int rem = task >> 5;          // 0..29
            int r   = rem / 10;
            int xx  = rem - r * 10;
            int gy = h + r - 1, gx = x0 + xx - 1;
            float4 A = make_float4(0.f,0.f,0.f,0.f), B = make_float4(0.f,0.f,0.f,0.f);
            if (gy >= 0 && gy < HH && gx >= 0 && gx < WW) {
                uint4 u = *(const uint4*)(inp + (((size_t)(n * HH + gy)) * WW + gx) * CC + c8 * 8);
                bfu2(u.x, A.x, A.y); bfu2(u.y, A.z, A.w);
                bfu2(u.z, B.x, B.y); bfu2(u.w, B.z, B.w);
            }
            *(float4*)&sx[(r * 10 + xx) * 256 + c8 * 8]     = A;
            *(float4*)&sx[(r * 10 + xx) * 256 + c8 * 8 + 4] = B;
        }
    }
    __syncthreads();

    int c = t;
    float wr[9];
    #pragma unroll
    for (int i = 0; i < 9; ++i) wr[i] = dww[c * 9 + i];
    float bias = dwb[c];
    float a[8];
    #pragma unroll
    for (int px = 0; px < 8; ++px) {
        float acc = bias;
        #pragma unroll
        for (int dy = 0; dy < 3; ++dy)
            #pragma unroll
            for (int dx = 0; dx < 3; ++dx)
                acc += sx[(dy * 10 + px + dx) * 256 + c] * wr[dy * 3 + dx];
        a[px] = acc;
    }

    int wid = t >> 6, lane = t & 63;
    #pragma unroll
    for (int px = 0; px < 8; ++px) {
        float s1 = a[px], s2 = a[px] * a[px];
        #pragma unroll
        for (int o = 1; o < 64; o <<= 1) {
            s1 += __shfl_xor(s1, o);
            s2 += __shfl_xor(s2, o);
        }
        if (lane == 0) { ls1[px][wid] = s1; ls2[px][wid] = s2; }
    }
    __syncthreads();

    float gam = lng[c], bet = lnb[c];
    #pragma unroll
    for (int px = 0; px < 8; ++px) {
        float t1 = ls1[px][0] + ls1[px][1] + ls1[px][2] + ls1[px][3];
        float t2 = ls2[px][0] + ls2[px][1] + ls2[px][2] + ls2[px][3];
        float mu  = t1 * (1.0f/256.0f);
        float var = t2 * (1.0f/256.0f) - mu * mu;
        float rr  = rsqrtf(var + 1e-5f);
        float v = (a[px] - mu) * rr * gam + bet;
        float g = 0.5f * v * (1.0f + erff(v * 0.70710678118654752440f));
        x1[(((size_t)(n * HH + h)) * WW + x0 + px) * CC + c] = __float2bfloat16(g);
    }
}

// ---------------------------------------------------------------------------
// GEMM staging (shared by all GEMM kernels)
__device__ __forceinline__ void stage_tile(const __hip_bfloat16* __restrict__ A,
                                           const __hip_bfloat16* __restrict__ Bt,
                                           __bf16* As, __bf16* Bs,
                                           int bm, int bn, int k0, int w, int l) {
    #pragma unroll
    for (int i = 0; i < 4; ++i) {
        int q = w*256 + i*64 + l;
        int row = q >> 3, sk = q & 7;
        const __hip_bfloat16* g = A + (((size_t)(bm + row)) << 8) + k0 + sk*8;
        GLOAD_LDS16(g, As + (w*256 + i*64)*8);
    }
    #pragma unroll
    for (int i = 0; i < 2; ++i) {
        int q = w*128 + i*64 + l;
        int row = q >> 3, sk = q & 7;
        const __hip_bfloat16* g = Bt + (((size_t)(bn + row)) << 8) + k0 + sk*8;
        GLOAD_LDS16(g, Bs + (w*128 + i*64)*8);
    }
}

// K3: bf16 MFMA GEMM. Tile 128x64, 4 waves, BK=64, dbuf. bf16 C-out.
__global__ void mgemm_kernel(const __hip_bfloat16* __restrict__ A,
                             const __hip_bfloat16* __restrict__ Bt,
                             const float* __restrict__ bias,
                             __hip_bfloat16* __restrict__ Cout, int ldc) {
    __shared__ __bf16 smem[24576];
    int tid = threadIdx.x;
    int w = tid >> 6, l = tid & 63;
    int bn = blockIdx.x * 64;
    int bm = blockIdx.y * 128;
    __bf16* Asb[2] = { smem,        smem + 12288 };
    __bf16* Bsb[2] = { smem + 8192, smem + 20480 };
    f32x4 acc[2][4];
    #pragma unroll
    for (int m = 0; m < 2; ++m)
        #pragma unroll
        for (int n = 0; n < 4; ++n)
            acc[m][n] = (f32x4){0.f, 0.f, 0.f, 0.f};

    stage_tile(A, Bt, Asb[0], Bsb[0], bm, bn, 0, w, l);
    __syncthreads();
    int lr = l & 15, kg = l >> 4;
    #pragma unroll
    for (int t = 0; t < 4; ++t) {
        int cur = t & 1;
        if (t < 3) stage_tile(A, Bt, Asb[cur^1], Bsb[cur^1], bm, bn, (t+1)*64, w, l);
        const __bf16* Ab = Asb[cur];
        const __bf16* Bb = Bsb[cur];
        bf16x8 af[2][2], bfr[4][2];
        #pragma unroll
        for (int m = 0; m < 2; ++m)
            #pragma unroll
            for (int u = 0; u < 2; ++u)
                af[m][u] = *(const bf16x8*)&Ab[(w*32 + m*16 + lr)*64 + u*32 + kg*8];
        #pragma unroll
        for (int n = 0; n < 4; ++n)
            #pragma unroll
            for (int u = 0; u < 2; ++u)
                bfr[n][u] = *(const bf16x8*)&Bb[(n*16 + lr)*64 + u*32 + kg*8];
        #pragma unroll
        for (int u = 0; u < 2; ++u)
            #pragma unroll
            for (int m = 0; m < 2; ++m)
                #pragma unroll
                for (int n = 0; n < 4; ++n)
                    acc[m][n] = __builtin_amdgcn_mfma_f32_16x16x32_bf16(af[m][u], bfr[n][u], acc[m][n], 0, 0, 0);
        __syncthreads();
    }
    int orow = bm + w*32 + kg*4;
    #pragma unroll
    for (int n = 0; n < 4; ++n) {
        int ccol = bn + n*16 + lr;
        float bv = bias[ccol];
        #pragma unroll
        for (int m = 0; m < 2; ++m) {
            #pragma unroll
            for (int j = 0; j < 4; ++j) {
                size_t o = (size_t)(orow + m*16 + j) * ldc + ccol;
                Cout[o] = __float2bfloat16(acc[m][n][j] + bv);
            }
        }
    }
}

// K3c: off+msk combined GEMM (N=432), column-routed epilogue.
__global__ void omgemm_kernel(const __hip_bfloat16* __restrict__ A,
                              const __hip_bfloat16* __restrict__ Bt,
                              const float* __restrict__ bias,
                              __hip_bfloat16* __restrict__ off_bf,
                              __hip_bfloat16* __restrict__ msk_bf) {
    __shared__ __bf16 smem[24576];
    int tid = threadIdx.x;
    int w = tid >> 6, l = tid & 63;
    int bn = blockIdx.x * 64;
    int bm = blockIdx.y * 128;
    __bf16* Asb[2] = { smem,        smem + 12288 };
    __bf16* Bsb[2] = { smem + 8192, smem + 20480 };
    f32x4 acc[2][4];
    #pragma unroll
    for (int m = 0; m < 2; ++m)
        #pragma unroll
        for (int n = 0; n < 4; ++n)
            acc[m][n] = (f32x4){0.f, 0.f, 0.f, 0.f};

    stage_tile(A, Bt, Asb[0], Bsb[0], bm, bn, 0, w, l);
    __syncthreads();
    int lr = l & 15, kg = l >> 4;
    #pragma unroll
    for (int t = 0; t < 4; ++t) {
        int cur = t & 1;
        if (t < 3) stage_tile(A, Bt, Asb[cur^1], Bsb[cur^1], bm, bn, (t+1)*64, w, l);
        const __bf16* Ab = Asb[cur];
        const __bf16* Bb = Bsb[cur];
        bf16x8 af[2][2], bfr[4][2];
        #pragma unroll
        for (int m = 0; m < 2; ++m)
            #pragma unroll
            for (int u = 0; u < 2; ++u)
                af[m][u] = *(const bf16x8*)&Ab[(w*32 + m*16 + lr)*64 + u*32 + kg*8];
        #pragma unroll
        for (int n = 0; n < 4; ++n)
            #pragma unroll
            for (int u = 0; u < 2; ++u)
                bfr[n][u] = *(const bf16x8*)&Bb[(n*16 + lr)*64 + u*32 + kg*8];
        #pragma unroll
        for (int u = 0; u < 2; ++u)
            #pragma unroll
            for (int m = 0; m < 2; ++m)
                #pragma unroll
                for (int n = 0; n < 4; ++n)
                    acc[m][n] = __builtin_amdgcn_mfma_f32_16x16x32_bf16(af[m][u], bfr[n][u], acc[m][n], 0, 0, 0);
        __syncthreads();
    }
    int orow = bm + w*32 + kg*4;
    #pragma unroll
    for (int n = 0; n < 4; ++n) {
        int ccol = bn + n*16 + lr;
        if (ccol >= 432) continue;
        float bv = bias[ccol];
        #pragma unroll
        for (int m = 0; m < 2; ++m) {
            #pragma unroll
            for (int j = 0; j < 4; ++j) {
                int row = orow + m*16 + j;
                float v = acc[m][n][j] + bv;
                if (ccol < 288)
                    off_bf[(size_t)row * 288 + ccol] = __float2bfloat16(v);
                else
                    msk_bf[(size_t)row * 144 + (ccol - 288)] = __float2bfloat16(v);
            }
        }
    }
}

// K3b: attn GEMM with fused finmul epilogue.
__global__ void attn_fused_kernel(const __hip_bfloat16* __restrict__ A,
                                  const __hip_bfloat16* __restrict__ Bt,
                                  const float* __restrict__ bias,
                                  const float* __restrict__ x,
                                  float* __restrict__ out) {
    __shared__ __bf16 smem[24576];   // staging; reused as fp32 C-tile in epilogue
    int tid = threadIdx.x;
    int w = tid >> 6, l = tid & 63;
    int bn = blockIdx.x * 64;
    int bm = blockIdx.y * 128;
    __bf16* Asb[2] = { smem,        smem + 12288 };
    __bf16* Bsb[2] = { smem + 8192, smem + 20480 };
    f32x4 acc[2][4];
    #pragma unroll
    for (int m = 0; m < 2; ++m)
        #pragma unroll
        for (int n = 0; n < 4; ++n)
            acc[m][n] = (f32x4){0.f, 0.f, 0.f, 0.f};

    stage_tile(A, Bt, Asb[0], Bsb[0], bm, bn, 0, w, l);
    __syncthreads();
    int lr = l & 15, kg = l >> 4;
    #pragma unroll
    for (int t = 0; t < 4; ++t) {
        int cur = t & 1;
        if (t < 3) stage_tile(A, Bt, Asb[cur^1], Bsb[cur^1], bm, bn, (t+1)*64, w, l);
        const __bf16* Ab = Asb[cur];
        const __bf16* Bb = Bsb[cur];
        bf16x8 af[2][2], bfr[4][2];
        #pragma unroll
        for (int m = 0; m < 2; ++m)
            #pragma unroll
            for (int u = 0; u < 2; ++u)
                af[m][u] = *(const bf16x8*)&Ab[(w*32 + m*16 + lr)*64 + u*32 + kg*8];
        #pragma unroll
        for (int n = 0; n < 4; ++n)
            #pragma unroll
            for (int u = 0; u < 2; ++u)
                bfr[n][u] = *(const bf16x8*)&Bb[(n*16 + lr)*64 + u*32 + kg*8];
        #pragma unroll
        for (int u = 0; u < 2; ++u)
            #pragma unroll
            for (int m = 0; m < 2; ++m)
                #pragma unroll
                for (int n = 0; n < 4; ++n)
                    acc[m][n] = __builtin_amdgcn_mfma_f32_16x16x32_bf16(af[m][u], bfr[n][u], acc[m][n], 0, 0, 0);
        __syncthreads();
    }

    // ---- epilogue: acc -> LDS [d][pix] fp32 (+bias), transpose, out = x*attn
    float* cLds = (float*)smem;              // [64][133] fp32 = 34048 B
    int rel0 = w*32 + kg*4;
    #pragma unroll
    for (int n = 0; n < 4; ++n) {
        int col = n*16 + lr;
        float bv = bias[bn + col];
        #pragma unroll
        for (int m = 0; m < 2; ++m) {
            #pragma unroll
            for (int j = 0; j < 4; ++j)
                cLds[col * 133 + rel0 + m*16 + j] = acc[m][n][j] + bv;
        }
    }
    __syncthreads();

    int d  = tid >> 2;                        // 0..63
    int po = (tid & 3) * 32;                  // pix offset within 128-tile
    int n_img = bm >> 12;
    int rem   = bm & 4095;
    size_t gb = (((size_t)(n_img * CC + bn + d)) << 12) + rem + po;
    const float* xr = x + gb;
    float* ow = out + gb;
    const float* cr = &cLds[d * 133 + po];
    #pragma unroll
    for (int j = 0; j < 32; j += 4) {
        float4 xv = *(const float4*)(xr + j);
        float4 r;
        r.x = xv.x * cr[j+0];
        r.y = xv.y * cr[j+1];
        r.z = xv.z * cr[j+2];
        r.w = xv.w * cr[j+3];
        *(float4*)(ow + j) = r;
    }
}

// ---------------------------------------------------------------------------
// K5 v8: DCNv3 core — fully fused per-thread: thread = (pixel, group), owns all
// 16 channels. No LDS, no barrier; softmax+decode once per (px,g); 32B corner
// loads; f32x2 packed FMA. XCD swizzle: each XCD owns one image.
__global__ void dcn_kernel(const __hip_bfloat16* __restrict__ xproj,
                           const __hip_bfloat16* __restrict__ off,
                           const __hip_bfloat16* __restrict__ mlog,
                           __hip_bfloat16* __restrict__ y) {
    int bid = blockIdx.x;                        // grid 2048 (%8==0)
    int blk = (bid & 7) * 256 + (bid >> 3);      // bijective XCD swizzle
    int task = blk * 256 + threadIdx.x;          // pix*16 + g
    int g   = task & 15;
    int pix = task >> 4;
    int wo = pix & 63, ho = (pix >> 6) & 63;
    int n  = pix >> 12;

    // ---- hoisted loads: 9 offsets (u32 pairs) + 9 mask logits ----
    const unsigned* ob = (const unsigned*)(off + (size_t)pix * 288 + g * 18);
    unsigned opk[9];
    #pragma unroll
    for (int p = 0; p < 9; ++p) opk[p] = ob[p];
    const __hip_bfloat16* mb = mlog + (size_t)pix * 144 + g * 9;
    float lg[9];
    float mx = -1e30f;
    #pragma unroll
    for (int p = 0; p < 9; ++p) { lg[p] = __bfloat162float(mb[p]); mx = fmaxf(mx, lg[p]); }
    float se = 0.f;
    #pragma unroll
    for (int p = 0; p < 9; ++p) { lg[p] = __expf(lg[p] - mx); se += lg[p]; }
    float rs = 1.0f / se;

    const __hip_bfloat16* xb = xproj + ((size_t)n << 20) + g * 16;
    f32x2 A[8];
    #pragma unroll
    for (int i = 0; i < 8; ++i) A[i] = (f32x2){0.f, 0.f};

    #pragma unroll
    for (int p = 0; p < 9; ++p) {
        float ox, oy;
        bfu2(opk[p], ox, oy);
        float m = lg[p] * rs;
        int dx = p / 3 - 1;                 // kw-major
        int dy = p - (p / 3) * 3 - 1;
        float fx = (float)(wo + dx) + ox;
        float fy = (float)(ho + dy) + oy;
        float x0f = floorf(fx), y0f = floorf(fy);
        int x0 = (int)x0f, y0 = (int)y0f;
        int x1 = x0 + 1, y1 = y0 + 1;
        float wx1 = fx - x0f, wx0 = 1.0f - wx1;
        float wy1 = fy - y0f, wy0 = 1.0f - wy1;
        float vx0 = (x0 >= 0 && x0 < WW) ? 1.0f : 0.0f;
        float vx1 = (x1 >= 0 && x1 < WW) ? 1.0f : 0.0f;
        float vy0 = (y0 >= 0 && y0 < HH) ? 1.0f : 0.0f;
        float vy1 = (y1 >= 0 && y1 < HH) ? 1.0f : 0.0f;
        int x0c = min(max(x0, 0), WW - 1), x1c = min(max(x1, 0), WW - 1);
        int y0c = min(max(y0, 0), HH - 1), y1c = min(max(y1, 0), HH - 1);
        float w00 = m * wy0 * wx0 * vy0 * vx0;
        float w01 = m * wy0 * wx1 * vy0 * vx1;
        float w10 = m * wy1 * wx0 * vy1 * vx0;
        float w11 = m * wy1 * wx1 * vy1 * vx1;
        int base = (y0c * WW + x0c) << 8;
        int ddx  = (x1c - x0c) << 8;
        int ddy  = (y1c - y0c) << 14;
        const __hip_bfloat16* c00 = xb + base;
        const __hip_bfloat16* c01 = xb + base + ddx;
        const __hip_bfloat16* c10 = xb + base + ddy;
        const __hip_bfloat16* c11 = xb + base + ddy + ddx;
        uint4 uA0 = *(const uint4*)c00,  uA1 = *(const uint4*)(c00 + 8);
        uint4 uB0 = *(const uint4*)c01,  uB1 = *(const uint4*)(c01 + 8);
        uint4 uC0 = *(const uint4*)c10,  uC1 = *(const uint4*)(c10 + 8);
        uint4 uD0 = *(const uint4*)c11,  uD1 = *(const uint4*)(c11 + 8);
        f32x2 wv;
        wv = (f32x2){w00, w00};
        A[0] += wv * bfup2(uA0.x); A[1] += wv * bfup2(uA0.y);
        A[2] += wv * bfup2(uA0.z); A[3] += wv * bfup2(uA0.w);
        A[4] += wv * bfup2(uA1.x); A[5] += wv * bfup2(uA1.y);
        A[6] += wv * bfup2(uA1.z); A[7] += wv * bfup2(uA1.w);
        wv = (f32x2){w01, w01};
        A[0] += wv * bfup2(uB0.x); A[1] += wv * bfup2(uB0.y);
        A[2] += wv * bfup2(uB0.z); A[3] += wv * bfup2(uB0.w);
        A[4] += wv * bfup2(uB1.x); A[5] += wv * bfup2(uB1.y);
        A[6] += wv * bfup2(uB1.z); A[7] += wv * bfup2(uB1.w);
        wv = (f32x2){w10, w10};
        A[0] += wv * bfup2(uC0.x); A[1] += wv * bfup2(uC0.y);
        A[2] += wv * bfup2(uC0.z); A[3] += wv * bfup2(uC0.w);
        A[4] += wv * bfup2(uC1.x); A[5] += wv * bfup2(uC1.y);
        A[6] += wv * bfup2(uC1.z); A[7] += wv * bfup2(uC1.w);
        wv = (f32x2){w11, w11};
        A[0] += wv * bfup2(uD0.x); A[1] += wv * bfup2(uD0.y);
        A[2] += wv * bfup2(uD0.z); A[3] += wv * bfup2(uD0.w);
        A[4] += wv * bfup2(uD1.x); A[5] += wv * bfup2(uD1.y);
        A[6] += wv * bfup2(uD1.z); A[7] += wv * bfup2(uD1.w);
    }

    union { __hip_bfloat16 h[16]; uint4 u[2]; } ov;
    #pragma unroll
    for (int i = 0; i < 8; ++i) {
        ov.h[2*i]   = __float2bfloat16(A[i].x);
        ov.h[2*i+1] = __float2bfloat16(A[i].y);
    }
    __hip_bfloat16* yp = y + (size_t)pix * CC + g * 16;
    *(uint4*)yp       = ov.u[0];
    *(uint4*)(yp + 8) = ov.u[1];
}

// ---------------------------------------------------------------------------
extern "C" void kernel_launch(void* const* d_in, const int* in_sizes, int n_in,
                              void* d_out, int out_size, void* d_ws, size_t ws_size,
                              hipStream_t stream) {
    const float* x      = (const float*)d_in[0];
    const float* conv0w = (const float*)d_in[1];
    const float* conv0b = (const float*)d_in[2];
    const float* dww    = (const float*)d_in[3];
    const float* dwb    = (const float*)d_in[4];
    const float* lng    = (const float*)d_in[5];
    const float* lnb    = (const float*)d_in[6];
    const float* offw   = (const float*)d_in[7];
    const float* offb   = (const float*)d_in[8];
    const float* mskw   = (const float*)d_in[9];
    const float* mskb   = (const float*)d_in[10];
    const float* inw    = (const float*)d_in[11];
    const float* inb    = (const float*)d_in[12];
    const float* outpw  = (const float*)d_in[13];
    const float* outpb  = (const float*)d_in[14];
    const float* pww    = (const float*)d_in[15];
    const float* pwb    = (const float*)d_in[16];

    __hip_bfloat16* bfb = (__hip_bfloat16*)d_ws;
    __hip_bfloat16* inp_bf  = bfb;                   // 8,388,608 (y_bf alias)
    __hip_bfloat16* y_bf    = inp_bf;
    __hip_bfloat16* x1_bf   = bfb + 8388608;         // (xpj_bf alias)
    __hip_bfloat16* xpj_bf  = x1_bf;
    __hip_bfloat16* off_bf  = bfb + 16777216;        // 9,437,184
    __hip_bfloat16* msk_bf  = bfb + 26214400;        // 4,718,592
    __hip_bfloat16* bt_in   = bfb + 30932992;        // 256*256
    __hip_bfloat16* bt_om   = bt_in + 65536;         // 448*256 (off|msk concat)
    __hip_bfloat16* bt_wc   = bt_om + 114688;        // 256*256 (combined outp*pw)
    float* bcomb = (float*)(bt_wc + 65536);          // 256 floats
    float* bcat  = bcomb + 256;                      // 448 floats
    float* out = (float*)d_out;

    // 0. merged weight prep
    prep_kernel<<<963, 256, 0, stream>>>(inw, offw, mskw, outpw, pww, outpb, pwb,
                                         offb, mskb, bt_in, bt_om, bt_wc, bcomb, bcat);
    // 1. conv0 5x5 dw -> inp_bf (bf16 only)
    conv0_kernel<<<dim3(8, 16, BB), 256, 0, stream>>>(x, conv0w, conv0b, inp_bf);
    // 2. dw3x3 + LN + GELU -> x1_bf
    dwln_kernel<<<dim3(8, 64, BB), 256, 0, stream>>>(inp_bf, dww, dwb, lng, lnb, x1_bf);
    // 3. [offset | mask logits] = x1 @ bt_om + bcat -> off_bf / msk_bf (one GEMM)
    omgemm_kernel<<<dim3(7, 256), 256, 0, stream>>>(x1_bf, bt_om, bcat, off_bf, msk_bf);
    // 4. xproj = inp @ in_w + in_b -> bf16 (overwrites x1 region; x1 dead)
    mgemm_kernel<<<dim3(4, 256), 256, 0, stream>>>(inp_bf, bt_in, inb, xpj_bf, 256);
    // 5. DCN core (fused per-thread, 16ch, XCD-swizzled) -> y_bf
    dcn_kernel<<<2048, 256, 0, stream>>>(xpj_bf, off_bf, msk_bf, y_bf);
    // 6. attn GEMM + fused finmul: out = x * (y @ Wc + bc)
    attn_fused_kernel<<<dim3(4, 256), 256, 0, stream>>>(y_bf, bt_wc, bcomb, x, out);
}

// Round 15
// 168.660 us; speedup vs baseline: 1.1892x; 1.1892x over previous
//
#include <hip/hip_runtime.h>
#include <hip/hip_bf16.h>
#include <hip/hip_fp16.h>
#include <math.h>

// Problem constants
#define BB 8
#define CC 256
#define HH 64
#define WW 64
#define GG 16
#define GCH 16
#define PP 9
#define NPIX (BB*HH*WW)   // 32768

typedef __attribute__((ext_vector_type(4))) float f32x4;
typedef __bf16 bf16x8 __attribute__((ext_vector_type(8)));

#define GLOAD_LDS16(g, l) __builtin_amdgcn_global_load_lds( \
    (const __attribute__((address_space(1))) unsigned int*)(g), \
    (__attribute__((address_space(3))) unsigned int*)(l), 16, 0, 0)

// unpack a u32 holding 2 bf16 -> 2 floats (elem0 = low 16 bits)
__device__ __forceinline__ void bfu2(unsigned a, float& lo, float& hi) {
    union { unsigned u; float f; } t0, t1;
    t0.u = a << 16; t1.u = a & 0xffff0000u;
    lo = t0.f; hi = t1.f;
}
__device__ __forceinline__ float bfu1(unsigned short a) {
    union { unsigned u; float f; } t;
    t.u = ((unsigned)a) << 16;
    return t.f;
}

// ---------------------------------------------------------------------------
// K0: merged weight prep.
__global__ void prep_kernel(const float* __restrict__ inw, const float* __restrict__ offw,
                            const float* __restrict__ mskw, const float* __restrict__ outpw,
                            const float* __restrict__ pww, const float* __restrict__ outpb,
                            const float* __restrict__ pwb, const float* __restrict__ offb,
                            const float* __restrict__ mskb,
                            __hip_bfloat16* __restrict__ bt_in, __hip_bfloat16* __restrict__ bt_om,
                            __hip_bfloat16* __restrict__ bt_wc, float* __restrict__ bcomb,
                            float* __restrict__ bcat) {
    __shared__ float pd[256];
    int bid = blockIdx.x;
    int t = threadIdx.x;
    if (bid < 256) {
        bt_in[bid * 256 + t] = __float2bfloat16(inw[t * 256 + bid]);
    } else if (bid < 704) {
        int n = bid - 256;    // 0..447
        float v = 0.0f;
        if (n < 288)      v = offw[t * 288 + n];
        else if (n < 432) v = mskw[t * 144 + (n - 288)];
        bt_om[(size_t)n * 256 + t] = __float2bfloat16(v);
    } else if (bid < 960) {
        int d = bid - 704;
        pd[t] = pww[d * 256 + t];
        __syncthreads();
        const float* ow = outpw + t * 256;
        float s = 0.0f;
        #pragma unroll 8
        for (int c = 0; c < 256; ++c) s += ow[c] * pd[c];
        bt_wc[d * 256 + t] = __float2bfloat16(s);
    } else if (bid == 960) {
        const float* pr = pww + t * 256;
        float s = pwb[t];
        #pragma unroll 8
        for (int c = 0; c < 256; ++c) s += outpb[c] * pr[c];
        bcomb[t] = s;
    } else {
        int i = (bid - 961) * 256 + t;    // 0..511
        if (i < 448) bcat[i] = (i < 288) ? offb[i] : (i < 432 ? mskb[i - 288] : 0.0f);
    }
}

// ---------------------------------------------------------------------------
// K1 v4: 5x5 depthwise conv, pad 2. x: NCHW fp32 -> out NHWC bf16 ONLY.
#define C0PLANE 817   // 12*68 + 1
__global__ void conv0_kernel(const float* __restrict__ x, const float* __restrict__ w,
                             const float* __restrict__ b,
                             __hip_bfloat16* __restrict__ out_bf) {
    __shared__ float sx[16 * C0PLANE];   // 52288 B
    int t  = threadIdx.x;
    int st = blockIdx.x;                 // row strip 0..7
    int cg = blockIdx.y;                 // channel group
    int n  = blockIdx.z;
    int h0 = st * 8;
    int c0 = cg * 16;

    #pragma unroll
    for (int i = 0; i < 12; ++i) {
        int task = i * 256 + t;
        int lane = task & 15;
        int pair = task >> 4;
        int c    = pair / 12;
        int row  = pair - c * 12;
        int gy   = h0 - 2 + row;
        float4 v = make_float4(0.f, 0.f, 0.f, 0.f);
        if (gy >= 0 && gy < HH)
            v = *(const float4*)(x + (((size_t)(n * CC + c0 + c)) * HH + gy) * WW + lane * 4);
        *(float4*)&sx[c * C0PLANE + row * 68 + 2 + lane * 4] = v;
    }
    if (t < 192) {
        int c = t / 12, row = t - (t / 12) * 12;
        float* p = &sx[c * C0PLANE + row * 68];
        p[0] = 0.f; p[1] = 0.f; p[66] = 0.f; p[67] = 0.f;
    }
    __syncthreads();

    int c = t & 15;
    int s = t >> 4;
    float wreg[25];
    const float* wp = w + (c0 + c) * 25;
    #pragma unroll
    for (int i = 0; i < 25; ++i) wreg[i] = wp[i];
    float bias = b[c0 + c];
    const float* cp = &sx[c * C0PLANE + s * 4];

    float win[5][8];
    #pragma unroll
    for (int rr = 0; rr < 4; ++rr)
        #pragma unroll
        for (int j = 0; j < 8; ++j) win[rr][j] = cp[rr * 68 + j];

    #pragma unroll
    for (int r = 0; r < 8; ++r) {
        #pragma unroll
        for (int j = 0; j < 8; ++j) win[(r + 4) % 5][j] = cp[(r + 4) * 68 + j];
        float a0 = bias, a1 = bias, a2 = bias, a3 = bias;
        #pragma unroll
        for (int dy = 0; dy < 5; ++dy) {
            const float* wr = &wreg[dy * 5];
            const float* wd = win[(r + dy) % 5];
            #pragma unroll
            for (int dx = 0; dx < 5; ++dx) {
                float wv = wr[dx];
                a0 += wd[0 + dx] * wv;
                a1 += wd[1 + dx] * wv;
                a2 += wd[2 + dx] * wv;
                a3 += wd[3 + dx] * wv;
            }
        }
        size_t pixb = ((size_t)n * 4096 + (h0 + r) * 64 + s * 4) << 8;
        out_bf[pixb + c0 + c]       = __float2bfloat16(a0);
        out_bf[pixb + 256 + c0 + c] = __float2bfloat16(a1);
        out_bf[pixb + 512 + c0 + c] = __float2bfloat16(a2);
        out_bf[pixb + 768 + c0 + c] = __float2bfloat16(a3);
    }
}

// ---------------------------------------------------------------------------
// K2 v4: 3x3 depthwise conv on bf16 NHWC + LayerNorm(C) + exact GELU -> x1.
// LDS halo stays PACKED bf16 (15.4 KB) -> 8 blocks/CU (thread-capped).
// Numerically identical to v3 (same bf16 values, unpacked at use).
__global__ void dwln_kernel(const __hip_bfloat16* __restrict__ inp, const float* __restrict__ dww,
                            const float* __restrict__ dwb, const float* __restrict__ lng,
                            const float* __restrict__ lnb, __hip_bfloat16* __restrict__ x1) {
    __shared__ unsigned short sxh[3 * 10 * 256];   // 15360 B
    __shared__ float ls1[8][4], ls2[8][4];
    int t  = threadIdx.x;
    int x0 = blockIdx.x * 8;
    int h  = blockIdx.y;
    int n  = blockIdx.z;

    // ---- stage halo: 30 sites x 32 x (8 bf16 ch) = 960 uint4 loads, packed ----
    #pragma unroll
    for (int i = 0; i < 4; ++i) {
        int task = i * 256 + t;          // 0..1023, need 960
        if (task < 960) {
            int c8  = task & 31;
            int rem = task >> 5;          // 0..29
            int r   = rem / 10;
            int xx  = rem - r * 10;
            int gy = h + r - 1, gx = x0 + xx - 1;
            uint4 u = make_uint4(0u, 0u, 0u, 0u);
            if (gy >= 0 && gy < HH && gx >= 0 && gx < WW)
                u = *(const uint4*)(inp + (((size_t)(n * HH + gy)) * WW + gx) * CC + c8 * 8);
            *(uint4*)&sxh[(r * 10 + xx) * 256 + c8 * 8] = u;
        }
    }
    __syncthreads();

    int c = t;
    float wr[9];
    #pragma unroll
    for (int i = 0; i < 9; ++i) wr[i] = dww[c * 9 + i];
    float bias = dwb[c];
    float a[8];
    #pragma unroll
    for (int px = 0; px < 8; ++px) {
        float acc = bias;
        #pragma unroll
        for (int dy = 0; dy < 3; ++dy)
            #pragma unroll
            for (int dx = 0; dx < 3; ++dx)
                acc += bfu1(sxh[(dy * 10 + px + dx) * 256 + c]) * wr[dy * 3 + dx];
        a[px] = acc;
    }

    int wid = t >> 6, lane = t & 63;
    #pragma unroll
    for (int px = 0; px < 8; ++px) {
        float s1 = a[px], s2 = a[px] * a[px];
        #pragma unroll
        for (int o = 1; o < 64; o <<= 1) {
            s1 += __shfl_xor(s1, o);
            s2 += __shfl_xor(s2, o);
        }
        if (lane == 0) { ls1[px][wid] = s1; ls2[px][wid] = s2; }
    }
    __syncthreads();

    float gam = lng[c], bet = lnb[c];
    #pragma unroll
    for (int px = 0; px < 8; ++px) {
        float t1 = ls1[px][0] + ls1[px][1] + ls1[px][2] + ls1[px][3];
        float t2 = ls2[px][0] + ls2[px][1] + ls2[px][2] + ls2[px][3];
        float mu  = t1 * (1.0f/256.0f);
        float var = t2 * (1.0f/256.0f) - mu * mu;
        float rr  = rsqrtf(var + 1e-5f);
        float v = (a[px] - mu) * rr * gam + bet;
        float g = 0.5f * v * (1.0f + erff(v * 0.70710678118654752440f));
        x1[(((size_t)(n * HH + h)) * WW + x0 + px) * CC + c] = __float2bfloat16(g);
    }
}

// ---------------------------------------------------------------------------
// GEMM staging (shared by all GEMM kernels)
__device__ __forceinline__ void stage_tile(const __hip_bfloat16* __restrict__ A,
                                           const __hip_bfloat16* __restrict__ Bt,
                                           __bf16* As, __bf16* Bs,
                                           int bm, int bn, int k0, int w, int l) {
    #pragma unroll
    for (int i = 0; i < 4; ++i) {
        int q = w*256 + i*64 + l;
        int row = q >> 3, sk = q & 7;
        const __hip_bfloat16* g = A + (((size_t)(bm + row)) << 8) + k0 + sk*8;
        GLOAD_LDS16(g, As + (w*256 + i*64)*8);
    }
    #pragma unroll
    for (int i = 0; i < 2; ++i) {
        int q = w*128 + i*64 + l;
        int row = q >> 3, sk = q & 7;
        const __hip_bfloat16* g = Bt + (((size_t)(bn + row)) << 8) + k0 + sk*8;
        GLOAD_LDS16(g, Bs + (w*128 + i*64)*8);
    }
}

// K3: bf16 MFMA GEMM. Tile 128x64, 4 waves, BK=64, dbuf. bf16 C-out.
__global__ void mgemm_kernel(const __hip_bfloat16* __restrict__ A,
                             const __hip_bfloat16* __restrict__ Bt,
                             const float* __restrict__ bias,
                             __hip_bfloat16* __restrict__ Cout, int ldc) {
    __shared__ __bf16 smem[24576];
    int tid = threadIdx.x;
    int w = tid >> 6, l = tid & 63;
    int bn = blockIdx.x * 64;
    int bm = blockIdx.y * 128;
    __bf16* Asb[2] = { smem,        smem + 12288 };
    __bf16* Bsb[2] = { smem + 8192, smem + 20480 };
    f32x4 acc[2][4];
    #pragma unroll
    for (int m = 0; m < 2; ++m)
        #pragma unroll
        for (int n = 0; n < 4; ++n)
            acc[m][n] = (f32x4){0.f, 0.f, 0.f, 0.f};

    stage_tile(A, Bt, Asb[0], Bsb[0], bm, bn, 0, w, l);
    __syncthreads();
    int lr = l & 15, kg = l >> 4;
    #pragma unroll
    for (int t = 0; t < 4; ++t) {
        int cur = t & 1;
        if (t < 3) stage_tile(A, Bt, Asb[cur^1], Bsb[cur^1], bm, bn, (t+1)*64, w, l);
        const __bf16* Ab = Asb[cur];
        const __bf16* Bb = Bsb[cur];
        bf16x8 af[2][2], bfr[4][2];
        #pragma unroll
        for (int m = 0; m < 2; ++m)
            #pragma unroll
            for (int u = 0; u < 2; ++u)
                af[m][u] = *(const bf16x8*)&Ab[(w*32 + m*16 + lr)*64 + u*32 + kg*8];
        #pragma unroll
        for (int n = 0; n < 4; ++n)
            #pragma unroll
            for (int u = 0; u < 2; ++u)
                bfr[n][u] = *(const bf16x8*)&Bb[(n*16 + lr)*64 + u*32 + kg*8];
        #pragma unroll
        for (int u = 0; u < 2; ++u)
            #pragma unroll
            for (int m = 0; m < 2; ++m)
                #pragma unroll
                for (int n = 0; n < 4; ++n)
                    acc[m][n] = __builtin_amdgcn_mfma_f32_16x16x32_bf16(af[m][u], bfr[n][u], acc[m][n], 0, 0, 0);
        __syncthreads();
    }
    int orow = bm + w*32 + kg*4;
    #pragma unroll
    for (int n = 0; n < 4; ++n) {
        int ccol = bn + n*16 + lr;
        float bv = bias[ccol];
        #pragma unroll
        for (int m = 0; m < 2; ++m) {
            #pragma unroll
            for (int j = 0; j < 4; ++j) {
                size_t o = (size_t)(orow + m*16 + j) * ldc + ccol;
                Cout[o] = __float2bfloat16(acc[m][n][j] + bv);
            }
        }
    }
}

// K3c: off+msk combined GEMM (N=432), column-routed epilogue.
__global__ void omgemm_kernel(const __hip_bfloat16* __restrict__ A,
                              const __hip_bfloat16* __restrict__ Bt,
                              const float* __restrict__ bias,
                              __hip_bfloat16* __restrict__ off_bf,
                              __hip_bfloat16* __restrict__ msk_bf) {
    __shared__ __bf16 smem[24576];
    int tid = threadIdx.x;
    int w = tid >> 6, l = tid & 63;
    int bn = blockIdx.x * 64;
    int bm = blockIdx.y * 128;
    __bf16* Asb[2] = { smem,        smem + 12288 };
    __bf16* Bsb[2] = { smem + 8192, smem + 20480 };
    f32x4 acc[2][4];
    #pragma unroll
    for (int m = 0; m < 2; ++m)
        #pragma unroll
        for (int n = 0; n < 4; ++n)
            acc[m][n] = (f32x4){0.f, 0.f, 0.f, 0.f};

    stage_tile(A, Bt, Asb[0], Bsb[0], bm, bn, 0, w, l);
    __syncthreads();
    int lr = l & 15, kg = l >> 4;
    #pragma unroll
    for (int t = 0; t < 4; ++t) {
        int cur = t & 1;
        if (t < 3) stage_tile(A, Bt, Asb[cur^1], Bsb[cur^1], bm, bn, (t+1)*64, w, l);
        const __bf16* Ab = Asb[cur];
        const __bf16* Bb = Bsb[cur];
        bf16x8 af[2][2], bfr[4][2];
        #pragma unroll
        for (int m = 0; m < 2; ++m)
            #pragma unroll
            for (int u = 0; u < 2; ++u)
                af[m][u] = *(const bf16x8*)&Ab[(w*32 + m*16 + lr)*64 + u*32 + kg*8];
        #pragma unroll
        for (int n = 0; n < 4; ++n)
            #pragma unroll
            for (int u = 0; u < 2; ++u)
                bfr[n][u] = *(const bf16x8*)&Bb[(n*16 + lr)*64 + u*32 + kg*8];
        #pragma unroll
        for (int u = 0; u < 2; ++u)
            #pragma unroll
            for (int m = 0; m < 2; ++m)
                #pragma unroll
                for (int n = 0; n < 4; ++n)
                    acc[m][n] = __builtin_amdgcn_mfma_f32_16x16x32_bf16(af[m][u], bfr[n][u], acc[m][n], 0, 0, 0);
        __syncthreads();
    }
    int orow = bm + w*32 + kg*4;
    #pragma unroll
    for (int n = 0; n < 4; ++n) {
        int ccol = bn + n*16 + lr;
        if (ccol >= 432) continue;
        float bv = bias[ccol];
        #pragma unroll
        for (int m = 0; m < 2; ++m) {
            #pragma unroll
            for (int j = 0; j < 4; ++j) {
                int row = orow + m*16 + j;
                float v = acc[m][n][j] + bv;
                if (ccol < 288)
                    off_bf[(size_t)row * 288 + ccol] = __float2bfloat16(v);
                else
                    msk_bf[(size_t)row * 144 + (ccol - 288)] = __float2bfloat16(v);
            }
        }
    }
}

// K3b: attn GEMM with fused finmul epilogue.
__global__ void attn_fused_kernel(const __hip_bfloat16* __restrict__ A,
                                  const __hip_bfloat16* __restrict__ Bt,
                                  const float* __restrict__ bias,
                                  const float* __restrict__ x,
                                  float* __restrict__ out) {
    __shared__ __bf16 smem[24576];   // staging; reused as fp32 C-tile in epilogue
    int tid = threadIdx.x;
    int w = tid >> 6, l = tid & 63;
    int bn = blockIdx.x * 64;
    int bm = blockIdx.y * 128;
    __bf16* Asb[2] = { smem,        smem + 12288 };
    __bf16* Bsb[2] = { smem + 8192, smem + 20480 };
    f32x4 acc[2][4];
    #pragma unroll
    for (int m = 0; m < 2; ++m)
        #pragma unroll
        for (int n = 0; n < 4; ++n)
            acc[m][n] = (f32x4){0.f, 0.f, 0.f, 0.f};

    stage_tile(A, Bt, Asb[0], Bsb[0], bm, bn, 0, w, l);
    __syncthreads();
    int lr = l & 15, kg = l >> 4;
    #pragma unroll
    for (int t = 0; t < 4; ++t) {
        int cur = t & 1;
        if (t < 3) stage_tile(A, Bt, Asb[cur^1], Bsb[cur^1], bm, bn, (t+1)*64, w, l);
        const __bf16* Ab = Asb[cur];
        const __bf16* Bb = Bsb[cur];
        bf16x8 af[2][2], bfr[4][2];
        #pragma unroll
        for (int m = 0; m < 2; ++m)
            #pragma unroll
            for (int u = 0; u < 2; ++u)
                af[m][u] = *(const bf16x8*)&Ab[(w*32 + m*16 + lr)*64 + u*32 + kg*8];
        #pragma unroll
        for (int n = 0; n < 4; ++n)
            #pragma unroll
            for (int u = 0; u < 2; ++u)
                bfr[n][u] = *(const bf16x8*)&Bb[(n*16 + lr)*64 + u*32 + kg*8];
        #pragma unroll
        for (int u = 0; u < 2; ++u)
            #pragma unroll
            for (int m = 0; m < 2; ++m)
                #pragma unroll
                for (int n = 0; n < 4; ++n)
                    acc[m][n] = __builtin_amdgcn_mfma_f32_16x16x32_bf16(af[m][u], bfr[n][u], acc[m][n], 0, 0, 0);
        __syncthreads();
    }

    // ---- epilogue: acc -> LDS [d][pix] fp32 (+bias), transpose, out = x*attn
    float* cLds = (float*)smem;              // [64][133] fp32 = 34048 B
    int rel0 = w*32 + kg*4;
    #pragma unroll
    for (int n = 0; n < 4; ++n) {
        int col = n*16 + lr;
        float bv = bias[bn + col];
        #pragma unroll
        for (int m = 0; m < 2; ++m) {
            #pragma unroll
            for (int j = 0; j < 4; ++j)
                cLds[col * 133 + rel0 + m*16 + j] = acc[m][n][j] + bv;
        }
    }
    __syncthreads();

    int d  = tid >> 2;                        // 0..63
    int po = (tid & 3) * 32;                  // pix offset within 128-tile
    int n_img = bm >> 12;
    int rem   = bm & 4095;
    size_t gb = (((size_t)(n_img * CC + bn + d)) << 12) + rem + po;
    const float* xr = x + gb;
    float* ow = out + gb;
    const float* cr = &cLds[d * 133 + po];
    #pragma unroll
    for (int j = 0; j < 32; j += 4) {
        float4 xv = *(const float4*)(xr + j);
        float4 r;
        r.x = xv.x * cr[j+0];
        r.y = xv.y * cr[j+1];
        r.z = xv.z * cr[j+2];
        r.w = xv.w * cr[j+3];
        *(float4*)(ow + j) = r;
    }
}

// ---------------------------------------------------------------------------
// K5 v7 (reverted R13): DCNv3 core, two-phase LDS, softmax fused, bf16 inputs,
// XCD swizzle. fp16-packed weights, packed corner offsets.
__global__ void dcn_kernel(const __hip_bfloat16* __restrict__ xproj,
                           const __hip_bfloat16* __restrict__ off,
                           const __hip_bfloat16* __restrict__ mlog,
                           __hip_bfloat16* __restrict__ y) {
    __shared__ uint2 wLds[1152];    // 9216 B
    __shared__ int   oLds[1152];    // 4608 B
    int bid = blockIdx.x;
    int blk = (bid & 7) * 512 + (bid >> 3);
    int pix0 = blk * 8;
    int t = threadIdx.x;

    // ---- phase 1: softmax + folded weights, thread per (px, g) ----
    if (t < 128) {
        int px = t >> 4;
        int g  = t & 15;
        int pix = pix0 + px;
        int wo = pix & 63, ho = (pix >> 6) & 63;
        const __hip_bfloat16* mb = mlog + (size_t)pix * 144 + g * 9;
        float lg[9];
        float mx = -1e30f;
        #pragma unroll
        for (int p = 0; p < 9; ++p) { lg[p] = __bfloat162float(mb[p]); mx = fmaxf(mx, lg[p]); }
        float se = 0.f;
        #pragma unroll
        for (int p = 0; p < 9; ++p) { lg[p] = __expf(lg[p] - mx); se += lg[p]; }
        float rs = 1.0f / se;
        const unsigned* ob = (const unsigned*)(off + (size_t)pix * 288 + g * 18);
        #pragma unroll
        for (int p = 0; p < 9; ++p) {
            float ox, oy;
            bfu2(ob[p], ox, oy);
            float m = lg[p] * rs;
            int dx = p / 3 - 1;                 // kw-major
            int dy = p - (p / 3) * 3 - 1;
            float fx = (float)(wo + dx) + ox;
            float fy = (float)(ho + dy) + oy;
            float x0f = floorf(fx), y0f = floorf(fy);
            int x0 = (int)x0f, y0 = (int)y0f;
            int x1 = x0 + 1, y1 = y0 + 1;
            float wx1 = fx - x0f, wx0 = 1.0f - wx1;
            float wy1 = fy - y0f, wy0 = 1.0f - wy1;
            float vx0 = (x0 >= 0 && x0 < WW) ? 1.0f : 0.0f;
            float vx1 = (x1 >= 0 && x1 < WW) ? 1.0f : 0.0f;
            float vy0 = (y0 >= 0 && y0 < HH) ? 1.0f : 0.0f;
            float vy1 = (y1 >= 0 && y1 < HH) ? 1.0f : 0.0f;
            int x0c = min(max(x0, 0), WW - 1), x1c = min(max(x1, 0), WW - 1);
            int y0c = min(max(y0, 0), HH - 1), y1c = min(max(y1, 0), HH - 1);
            int tau = px * 144 + g * 9 + p;
            union { __half2 h2; unsigned u; } pa, pb;
            pa.h2 = __floats2half2_rn(m * wy0 * wx0 * vy0 * vx0,
                                      m * wy0 * wx1 * vy0 * vx1);
            pb.h2 = __floats2half2_rn(m * wy1 * wx0 * vy1 * vx0,
                                      m * wy1 * wx1 * vy1 * vx1);
            wLds[tau] = make_uint2(pa.u, pb.u);
            oLds[tau] = (y0c * WW + x0c) | ((x1c - x0c) << 12) | ((y1c - y0c) << 13);
        }
    }
    __syncthreads();

    // ---- phase 2: gather 8 channels per thread ----
    int px = t >> 5;
    int l  = t & 31;
    int g  = l >> 1;
    int ch = g * 16 + (l & 1) * 8;
    int pix = pix0 + px;
    int n = pix >> 12;
    const __hip_bfloat16* xb = xproj + ((size_t)n << 20) + ch;
    float a0=0,a1=0,a2=0,a3=0,a4=0,a5=0,a6=0,a7=0;
    const uint2* wp = &wLds[px * 144 + g * 9];
    const int*   op = &oLds[px * 144 + g * 9];
    #pragma unroll
    for (int p = 0; p < 9; ++p) {
        uint2 pw = wp[p];
        union { unsigned u; __half2 h2; } ua, ub;
        ua.u = pw.x; ub.u = pw.y;
        float2 fA = __half22float2(ua.h2);
        float2 fB = __half22float2(ub.h2);
        float w00 = fA.x, w01 = fA.y, w10 = fB.x, w11 = fB.y;
        int pk = op[p];
        int base = (pk & 4095) << 8;
        int ddx  = ((pk >> 12) & 1) << 8;    // +1 col  = +256 elems
        int ddy  = ((pk >> 13) & 1) << 14;   // +1 row  = +16384 elems
        {
            uint4 u = *(const uint4*)(xb + base);
            float b0,b1,b2,b3,b4,b5,b6,b7;
            bfu2(u.x,b0,b1); bfu2(u.y,b2,b3); bfu2(u.z,b4,b5); bfu2(u.w,b6,b7);
            a0 += w00*b0; a1 += w00*b1; a2 += w00*b2; a3 += w00*b3;
            a4 += w00*b4; a5 += w00*b5; a6 += w00*b6; a7 += w00*b7;
        }
        {
            uint4 u = *(const uint4*)(xb + base + ddx);
            float b0,b1,b2,b3,b4,b5,b6,b7;
            bfu2(u.x,b0,b1); bfu2(u.y,b2,b3); bfu2(u.z,b4,b5); bfu2(u.w,b6,b7);
            a0 += w01*b0; a1 += w01*b1; a2 += w01*b2; a3 += w01*b3;
            a4 += w01*b4; a5 += w01*b5; a6 += w01*b6; a7 += w01*b7;
        }
        {
            uint4 u = *(const uint4*)(xb + base + ddy);
            float b0,b1,b2,b3,b4,b5,b6,b7;
            bfu2(u.x,b0,b1); bfu2(u.y,b2,b3); bfu2(u.z,b4,b5); bfu2(u.w,b6,b7);
            a0 += w10*b0; a1 += w10*b1; a2 += w10*b2; a3 += w10*b3;
            a4 += w10*b4; a5 += w10*b5; a6 += w10*b6; a7 += w10*b7;
        }
        {
            uint4 u = *(const uint4*)(xb + base + ddy + ddx);
            float b0,b1,b2,b3,b4,b5,b6,b7;
            bfu2(u.x,b0,b1); bfu2(u.y,b2,b3); bfu2(u.z,b4,b5); bfu2(u.w,b6,b7);
            a0 += w11*b0; a1 += w11*b1; a2 += w11*b2; a3 += w11*b3;
            a4 += w11*b4; a5 += w11*b5; a6 += w11*b6; a7 += w11*b7;
        }
    }
    union { __hip_bfloat16 h[8]; uint4 u; } ov;
    ov.h[0]=__float2bfloat16(a0); ov.h[1]=__float2bfloat16(a1);
    ov.h[2]=__float2bfloat16(a2); ov.h[3]=__float2bfloat16(a3);
    ov.h[4]=__float2bfloat16(a4); ov.h[5]=__float2bfloat16(a5);
    ov.h[6]=__float2bfloat16(a6); ov.h[7]=__float2bfloat16(a7);
    *(uint4*)(y + (size_t)pix * CC + ch) = ov.u;
}

// ---------------------------------------------------------------------------
extern "C" void kernel_launch(void* const* d_in, const int* in_sizes, int n_in,
                              void* d_out, int out_size, void* d_ws, size_t ws_size,
                              hipStream_t stream) {
    const float* x      = (const float*)d_in[0];
    const float* conv0w = (const float*)d_in[1];
    const float* conv0b = (const float*)d_in[2];
    const float* dww    = (const float*)d_in[3];
    const float* dwb    = (const float*)d_in[4];
    const float* lng    = (const float*)d_in[5];
    const float* lnb    = (const float*)d_in[6];
    const float* offw   = (const float*)d_in[7];
    const float* offb   = (const float*)d_in[8];
    const float* mskw   = (const float*)d_in[9];
    const float* mskb   = (const float*)d_in[10];
    const float* inw    = (const float*)d_in[11];
    const float* inb    = (const float*)d_in[12];
    const float* outpw  = (const float*)d_in[13];
    const float* outpb  = (const float*)d_in[14];
    const float* pww    = (const float*)d_in[15];
    const float* pwb    = (const float*)d_in[16];

    __hip_bfloat16* bfb = (__hip_bfloat16*)d_ws;
    __hip_bfloat16* inp_bf  = bfb;                   // 8,388,608 (y_bf alias)
    __hip_bfloat16* y_bf    = inp_bf;
    __hip_bfloat16* x1_bf   = bfb + 8388608;         // (xpj_bf alias)
    __hip_bfloat16* xpj_bf  = x1_bf;
    __hip_bfloat16* off_bf  = bfb + 16777216;        // 9,437,184
    __hip_bfloat16* msk_bf  = bfb + 26214400;        // 4,718,592
    __hip_bfloat16* bt_in   = bfb + 30932992;        // 256*256
    __hip_bfloat16* bt_om   = bt_in + 65536;         // 448*256 (off|msk concat)
    __hip_bfloat16* bt_wc   = bt_om + 114688;        // 256*256 (combined outp*pw)
    float* bcomb = (float*)(bt_wc + 65536);          // 256 floats
    float* bcat  = bcomb + 256;                      // 448 floats
    float* out = (float*)d_out;

    // 0. merged weight prep
    prep_kernel<<<963, 256, 0, stream>>>(inw, offw, mskw, outpw, pww, outpb, pwb,
                                         offb, mskb, bt_in, bt_om, bt_wc, bcomb, bcat);
    // 1. conv0 5x5 dw -> inp_bf (bf16 only)
    conv0_kernel<<<dim3(8, 16, BB), 256, 0, stream>>>(x, conv0w, conv0b, inp_bf);
    // 2. dw3x3 + LN + GELU -> x1_bf (packed-bf16 LDS halo)
    dwln_kernel<<<dim3(8, 64, BB), 256, 0, stream>>>(inp_bf, dww, dwb, lng, lnb, x1_bf);
    // 3. [offset | mask logits] = x1 @ bt_om + bcat -> off_bf / msk_bf (one GEMM)
    omgemm_kernel<<<dim3(7, 256), 256, 0, stream>>>(x1_bf, bt_om, bcat, off_bf, msk_bf);
    // 4. xproj = inp @ in_w + in_b -> bf16 (overwrites x1 region; x1 dead)
    mgemm_kernel<<<dim3(4, 256), 256, 0, stream>>>(inp_bf, bt_in, inb, xpj_bf, 256);
    // 5. DCN core (two-phase, XCD-swizzled; R13 revert) -> y_bf
    dcn_kernel<<<NPIX/8, 256, 0, stream>>>(xpj_bf, off_bf, msk_bf, y_bf);
    // 6. attn GEMM + fused finmul: out = x * (y @ Wc + bc)
    attn_fused_kernel<<<dim3(4, 256), 256, 0, stream>>>(y_bf, bt_wc, bcomb, x, out);
}

// Round 16
// 168.066 us; speedup vs baseline: 1.1934x; 1.0035x over previous
//
#include <hip/hip_runtime.h>
#include <hip/hip_bf16.h>
#include <hip/hip_fp16.h>
#include <math.h>

// Problem constants
#define BB 8
#define CC 256
#define HH 64
#define WW 64
#define GG 16
#define GCH 16
#define PP 9
#define NPIX (BB*HH*WW)   // 32768

typedef __attribute__((ext_vector_type(4))) float f32x4;
typedef __bf16 bf16x8 __attribute__((ext_vector_type(8)));

#define GLOAD_LDS16(g, l) __builtin_amdgcn_global_load_lds( \
    (const __attribute__((address_space(1))) unsigned int*)(g), \
    (__attribute__((address_space(3))) unsigned int*)(l), 16, 0, 0)

// unpack a u32 holding 2 bf16 -> 2 floats (elem0 = low 16 bits)
__device__ __forceinline__ void bfu2(unsigned a, float& lo, float& hi) {
    union { unsigned u; float f; } t0, t1;
    t0.u = a << 16; t1.u = a & 0xffff0000u;
    lo = t0.f; hi = t1.f;
}
__device__ __forceinline__ float bfu1(unsigned short a) {
    union { unsigned u; float f; } t;
    t.u = ((unsigned)a) << 16;
    return t.f;
}

// ---------------------------------------------------------------------------
// K0: merged weight prep.
__global__ void prep_kernel(const float* __restrict__ inw, const float* __restrict__ offw,
                            const float* __restrict__ mskw, const float* __restrict__ outpw,
                            const float* __restrict__ pww, const float* __restrict__ outpb,
                            const float* __restrict__ pwb, const float* __restrict__ offb,
                            const float* __restrict__ mskb,
                            __hip_bfloat16* __restrict__ bt_in, __hip_bfloat16* __restrict__ bt_om,
                            __hip_bfloat16* __restrict__ bt_wc, float* __restrict__ bcomb,
                            float* __restrict__ bcat) {
    __shared__ float pd[256];
    int bid = blockIdx.x;
    int t = threadIdx.x;
    if (bid < 256) {
        bt_in[bid * 256 + t] = __float2bfloat16(inw[t * 256 + bid]);
    } else if (bid < 704) {
        int n = bid - 256;    // 0..447
        float v = 0.0f;
        if (n < 288)      v = offw[t * 288 + n];
        else if (n < 432) v = mskw[t * 144 + (n - 288)];
        bt_om[(size_t)n * 256 + t] = __float2bfloat16(v);
    } else if (bid < 960) {
        int d = bid - 704;
        pd[t] = pww[d * 256 + t];
        __syncthreads();
        const float* ow = outpw + t * 256;
        float s = 0.0f;
        #pragma unroll 8
        for (int c = 0; c < 256; ++c) s += ow[c] * pd[c];
        bt_wc[d * 256 + t] = __float2bfloat16(s);
    } else if (bid == 960) {
        const float* pr = pww + t * 256;
        float s = pwb[t];
        #pragma unroll 8
        for (int c = 0; c < 256; ++c) s += outpb[c] * pr[c];
        bcomb[t] = s;
    } else {
        int i = (bid - 961) * 256 + t;    // 0..511
        if (i < 448) bcat[i] = (i < 288) ? offb[i] : (i < 432 ? mskb[i - 288] : 0.0f);
    }
}

// ---------------------------------------------------------------------------
// K1 v4: 5x5 depthwise conv, pad 2. x: NCHW fp32 -> out NHWC bf16 ONLY.
#define C0PLANE 817   // 12*68 + 1
__global__ void conv0_kernel(const float* __restrict__ x, const float* __restrict__ w,
                             const float* __restrict__ b,
                             __hip_bfloat16* __restrict__ out_bf) {
    __shared__ float sx[16 * C0PLANE];   // 52288 B
    int t  = threadIdx.x;
    int st = blockIdx.x;                 // row strip 0..7
    int cg = blockIdx.y;                 // channel group
    int n  = blockIdx.z;
    int h0 = st * 8;
    int c0 = cg * 16;

    #pragma unroll
    for (int i = 0; i < 12; ++i) {
        int task = i * 256 + t;
        int lane = task & 15;
        int pair = task >> 4;
        int c    = pair / 12;
        int row  = pair - c * 12;
        int gy   = h0 - 2 + row;
        float4 v = make_float4(0.f, 0.f, 0.f, 0.f);
        if (gy >= 0 && gy < HH)
            v = *(const float4*)(x + (((size_t)(n * CC + c0 + c)) * HH + gy) * WW + lane * 4);
        *(float4*)&sx[c * C0PLANE + row * 68 + 2 + lane * 4] = v;
    }
    if (t < 192) {
        int c = t / 12, row = t - (t / 12) * 12;
        float* p = &sx[c * C0PLANE + row * 68];
        p[0] = 0.f; p[1] = 0.f; p[66] = 0.f; p[67] = 0.f;
    }
    __syncthreads();

    int c = t & 15;
    int s = t >> 4;
    float wreg[25];
    const float* wp = w + (c0 + c) * 25;
    #pragma unroll
    for (int i = 0; i < 25; ++i) wreg[i] = wp[i];
    float bias = b[c0 + c];
    const float* cp = &sx[c * C0PLANE + s * 4];

    float win[5][8];
    #pragma unroll
    for (int rr = 0; rr < 4; ++rr)
        #pragma unroll
        for (int j = 0; j < 8; ++j) win[rr][j] = cp[rr * 68 + j];

    #pragma unroll
    for (int r = 0; r < 8; ++r) {
        #pragma unroll
        for (int j = 0; j < 8; ++j) win[(r + 4) % 5][j] = cp[(r + 4) * 68 + j];
        float a0 = bias, a1 = bias, a2 = bias, a3 = bias;
        #pragma unroll
        for (int dy = 0; dy < 5; ++dy) {
            const float* wr = &wreg[dy * 5];
            const float* wd = win[(r + dy) % 5];
            #pragma unroll
            for (int dx = 0; dx < 5; ++dx) {
                float wv = wr[dx];
                a0 += wd[0 + dx] * wv;
                a1 += wd[1 + dx] * wv;
                a2 += wd[2 + dx] * wv;
                a3 += wd[3 + dx] * wv;
            }
        }
        size_t pixb = ((size_t)n * 4096 + (h0 + r) * 64 + s * 4) << 8;
        out_bf[pixb + c0 + c]       = __float2bfloat16(a0);
        out_bf[pixb + 256 + c0 + c] = __float2bfloat16(a1);
        out_bf[pixb + 512 + c0 + c] = __float2bfloat16(a2);
        out_bf[pixb + 768 + c0 + c] = __float2bfloat16(a3);
    }
}

// ---------------------------------------------------------------------------
// K2 v4: 3x3 depthwise conv on bf16 NHWC + LayerNorm(C) + exact GELU -> x1.
__global__ void dwln_kernel(const __hip_bfloat16* __restrict__ inp, const float* __restrict__ dww,
                            const float* __restrict__ dwb, const float* __restrict__ lng,
                            const float* __restrict__ lnb, __hip_bfloat16* __restrict__ x1) {
    __shared__ unsigned short sxh[3 * 10 * 256];   // 15360 B
    __shared__ float ls1[8][4], ls2[8][4];
    int t  = threadIdx.x;
    int x0 = blockIdx.x * 8;
    int h  = blockIdx.y;
    int n  = blockIdx.z;

    #pragma unroll
    for (int i = 0; i < 4; ++i) {
        int task = i * 256 + t;          // 0..1023, need 960
        if (task < 960) {
            int c8  = task & 31;
            int rem = task >> 5;          // 0..29
            int r   = rem / 10;
            int xx  = rem - r * 10;
            int gy = h + r - 1, gx = x0 + xx - 1;
            uint4 u = make_uint4(0u, 0u, 0u, 0u);
            if (gy >= 0 && gy < HH && gx >= 0 && gx < WW)
                u = *(const uint4*)(inp + (((size_t)(n * HH + gy)) * WW + gx) * CC + c8 * 8);
            *(uint4*)&sxh[(r * 10 + xx) * 256 + c8 * 8] = u;
        }
    }
    __syncthreads();

    int c = t;
    float wr[9];
    #pragma unroll
    for (int i = 0; i < 9; ++i) wr[i] = dww[c * 9 + i];
    float bias = dwb[c];
    float a[8];
    #pragma unroll
    for (int px = 0; px < 8; ++px) {
        float acc = bias;
        #pragma unroll
        for (int dy = 0; dy < 3; ++dy)
            #pragma unroll
            for (int dx = 0; dx < 3; ++dx)
                acc += bfu1(sxh[(dy * 10 + px + dx) * 256 + c]) * wr[dy * 3 + dx];
        a[px] = acc;
    }

    int wid = t >> 6, lane = t & 63;
    #pragma unroll
    for (int px = 0; px < 8; ++px) {
        float s1 = a[px], s2 = a[px] * a[px];
        #pragma unroll
        for (int o = 1; o < 64; o <<= 1) {
            s1 += __shfl_xor(s1, o);
            s2 += __shfl_xor(s2, o);
        }
        if (lane == 0) { ls1[px][wid] = s1; ls2[px][wid] = s2; }
    }
    __syncthreads();

    float gam = lng[c], bet = lnb[c];
    #pragma unroll
    for (int px = 0; px < 8; ++px) {
        float t1 = ls1[px][0] + ls1[px][1] + ls1[px][2] + ls1[px][3];
        float t2 = ls2[px][0] + ls2[px][1] + ls2[px][2] + ls2[px][3];
        float mu  = t1 * (1.0f/256.0f);
        float var = t2 * (1.0f/256.0f) - mu * mu;
        float rr  = rsqrtf(var + 1e-5f);
        float v = (a[px] - mu) * rr * gam + bet;
        float g = 0.5f * v * (1.0f + erff(v * 0.70710678118654752440f));
        x1[(((size_t)(n * HH + h)) * WW + x0 + px) * CC + c] = __float2bfloat16(g);
    }
}

// ---------------------------------------------------------------------------
// GEMM staging (shared by all GEMM kernels)
__device__ __forceinline__ void stage_tile(const __hip_bfloat16* __restrict__ A,
                                           const __hip_bfloat16* __restrict__ Bt,
                                           __bf16* As, __bf16* Bs,
                                           int bm, int bn, int k0, int w, int l) {
    #pragma unroll
    for (int i = 0; i < 4; ++i) {
        int q = w*256 + i*64 + l;
        int row = q >> 3, sk = q & 7;
        const __hip_bfloat16* g = A + (((size_t)(bm + row)) << 8) + k0 + sk*8;
        GLOAD_LDS16(g, As + (w*256 + i*64)*8);
    }
    #pragma unroll
    for (int i = 0; i < 2; ++i) {
        int q = w*128 + i*64 + l;
        int row = q >> 3, sk = q & 7;
        const __hip_bfloat16* g = Bt + (((size_t)(bn + row)) << 8) + k0 + sk*8;
        GLOAD_LDS16(g, Bs + (w*128 + i*64)*8);
    }
}

// K3: bf16 MFMA GEMM. Tile 128x64, 4 waves, BK=64, dbuf. bf16 C-out.
__global__ void mgemm_kernel(const __hip_bfloat16* __restrict__ A,
                             const __hip_bfloat16* __restrict__ Bt,
                             const float* __restrict__ bias,
                             __hip_bfloat16* __restrict__ Cout, int ldc) {
    __shared__ __bf16 smem[24576];
    int tid = threadIdx.x;
    int w = tid >> 6, l = tid & 63;
    int bn = blockIdx.x * 64;
    int bm = blockIdx.y * 128;
    __bf16* Asb[2] = { smem,        smem + 12288 };
    __bf16* Bsb[2] = { smem + 8192, smem + 20480 };
    f32x4 acc[2][4];
    #pragma unroll
    for (int m = 0; m < 2; ++m)
        #pragma unroll
        for (int n = 0; n < 4; ++n)
            acc[m][n] = (f32x4){0.f, 0.f, 0.f, 0.f};

    stage_tile(A, Bt, Asb[0], Bsb[0], bm, bn, 0, w, l);
    __syncthreads();
    int lr = l & 15, kg = l >> 4;
    #pragma unroll
    for (int t = 0; t < 4; ++t) {
        int cur = t & 1;
        if (t < 3) stage_tile(A, Bt, Asb[cur^1], Bsb[cur^1], bm, bn, (t+1)*64, w, l);
        const __bf16* Ab = Asb[cur];
        const __bf16* Bb = Bsb[cur];
        bf16x8 af[2][2], bfr[4][2];
        #pragma unroll
        for (int m = 0; m < 2; ++m)
            #pragma unroll
            for (int u = 0; u < 2; ++u)
                af[m][u] = *(const bf16x8*)&Ab[(w*32 + m*16 + lr)*64 + u*32 + kg*8];
        #pragma unroll
        for (int n = 0; n < 4; ++n)
            #pragma unroll
            for (int u = 0; u < 2; ++u)
                bfr[n][u] = *(const bf16x8*)&Bb[(n*16 + lr)*64 + u*32 + kg*8];
        #pragma unroll
        for (int u = 0; u < 2; ++u)
            #pragma unroll
            for (int m = 0; m < 2; ++m)
                #pragma unroll
                for (int n = 0; n < 4; ++n)
                    acc[m][n] = __builtin_amdgcn_mfma_f32_16x16x32_bf16(af[m][u], bfr[n][u], acc[m][n], 0, 0, 0);
        __syncthreads();
    }
    int orow = bm + w*32 + kg*4;
    #pragma unroll
    for (int n = 0; n < 4; ++n) {
        int ccol = bn + n*16 + lr;
        float bv = bias[ccol];
        #pragma unroll
        for (int m = 0; m < 2; ++m) {
            #pragma unroll
            for (int j = 0; j < 4; ++j) {
                size_t o = (size_t)(orow + m*16 + j) * ldc + ccol;
                Cout[o] = __float2bfloat16(acc[m][n][j] + bv);
            }
        }
    }
}

// K3c: off+msk combined GEMM (N=432), column-routed epilogue.
__global__ void omgemm_kernel(const __hip_bfloat16* __restrict__ A,
                              const __hip_bfloat16* __restrict__ Bt,
                              const float* __restrict__ bias,
                              __hip_bfloat16* __restrict__ off_bf,
                              __hip_bfloat16* __restrict__ msk_bf) {
    __shared__ __bf16 smem[24576];
    int tid = threadIdx.x;
    int w = tid >> 6, l = tid & 63;
    int bn = blockIdx.x * 64;
    int bm = blockIdx.y * 128;
    __bf16* Asb[2] = { smem,        smem + 12288 };
    __bf16* Bsb[2] = { smem + 8192, smem + 20480 };
    f32x4 acc[2][4];
    #pragma unroll
    for (int m = 0; m < 2; ++m)
        #pragma unroll
        for (int n = 0; n < 4; ++n)
            acc[m][n] = (f32x4){0.f, 0.f, 0.f, 0.f};

    stage_tile(A, Bt, Asb[0], Bsb[0], bm, bn, 0, w, l);
    __syncthreads();
    int lr = l & 15, kg = l >> 4;
    #pragma unroll
    for (int t = 0; t < 4; ++t) {
        int cur = t & 1;
        if (t < 3) stage_tile(A, Bt, Asb[cur^1], Bsb[cur^1], bm, bn, (t+1)*64, w, l);
        const __bf16* Ab = Asb[cur];
        const __bf16* Bb = Bsb[cur];
        bf16x8 af[2][2], bfr[4][2];
        #pragma unroll
        for (int m = 0; m < 2; ++m)
            #pragma unroll
            for (int u = 0; u < 2; ++u)
                af[m][u] = *(const bf16x8*)&Ab[(w*32 + m*16 + lr)*64 + u*32 + kg*8];
        #pragma unroll
        for (int n = 0; n < 4; ++n)
            #pragma unroll
            for (int u = 0; u < 2; ++u)
                bfr[n][u] = *(const bf16x8*)&Bb[(n*16 + lr)*64 + u*32 + kg*8];
        #pragma unroll
        for (int u = 0; u < 2; ++u)
            #pragma unroll
            for (int m = 0; m < 2; ++m)
                #pragma unroll
                for (int n = 0; n < 4; ++n)
                    acc[m][n] = __builtin_amdgcn_mfma_f32_16x16x32_bf16(af[m][u], bfr[n][u], acc[m][n], 0, 0, 0);
        __syncthreads();
    }
    int orow = bm + w*32 + kg*4;
    #pragma unroll
    for (int n = 0; n < 4; ++n) {
        int ccol = bn + n*16 + lr;
        if (ccol >= 432) continue;
        float bv = bias[ccol];
        #pragma unroll
        for (int m = 0; m < 2; ++m) {
            #pragma unroll
            for (int j = 0; j < 4; ++j) {
                int row = orow + m*16 + j;
                float v = acc[m][n][j] + bv;
                if (ccol < 288)
                    off_bf[(size_t)row * 288 + ccol] = __float2bfloat16(v);
                else
                    msk_bf[(size_t)row * 144 + (ccol - 288)] = __float2bfloat16(v);
            }
        }
    }
}

// K3b: attn GEMM with fused finmul epilogue.
__global__ void attn_fused_kernel(const __hip_bfloat16* __restrict__ A,
                                  const __hip_bfloat16* __restrict__ Bt,
                                  const float* __restrict__ bias,
                                  const float* __restrict__ x,
                                  float* __restrict__ out) {
    __shared__ __bf16 smem[24576];   // staging; reused as fp32 C-tile in epilogue
    int tid = threadIdx.x;
    int w = tid >> 6, l = tid & 63;
    int bn = blockIdx.x * 64;
    int bm = blockIdx.y * 128;
    __bf16* Asb[2] = { smem,        smem + 12288 };
    __bf16* Bsb[2] = { smem + 8192, smem + 20480 };
    f32x4 acc[2][4];
    #pragma unroll
    for (int m = 0; m < 2; ++m)
        #pragma unroll
        for (int n = 0; n < 4; ++n)
            acc[m][n] = (f32x4){0.f, 0.f, 0.f, 0.f};

    stage_tile(A, Bt, Asb[0], Bsb[0], bm, bn, 0, w, l);
    __syncthreads();
    int lr = l & 15, kg = l >> 4;
    #pragma unroll
    for (int t = 0; t < 4; ++t) {
        int cur = t & 1;
        if (t < 3) stage_tile(A, Bt, Asb[cur^1], Bsb[cur^1], bm, bn, (t+1)*64, w, l);
        const __bf16* Ab = Asb[cur];
        const __bf16* Bb = Bsb[cur];
        bf16x8 af[2][2], bfr[4][2];
        #pragma unroll
        for (int m = 0; m < 2; ++m)
            #pragma unroll
            for (int u = 0; u < 2; ++u)
                af[m][u] = *(const bf16x8*)&Ab[(w*32 + m*16 + lr)*64 + u*32 + kg*8];
        #pragma unroll
        for (int n = 0; n < 4; ++n)
            #pragma unroll
            for (int u = 0; u < 2; ++u)
                bfr[n][u] = *(const bf16x8*)&Bb[(n*16 + lr)*64 + u*32 + kg*8];
        #pragma unroll
        for (int u = 0; u < 2; ++u)
            #pragma unroll
            for (int m = 0; m < 2; ++m)
                #pragma unroll
                for (int n = 0; n < 4; ++n)
                    acc[m][n] = __builtin_amdgcn_mfma_f32_16x16x32_bf16(af[m][u], bfr[n][u], acc[m][n], 0, 0, 0);
        __syncthreads();
    }

    // ---- epilogue: acc -> LDS [d][pix] fp32 (+bias), transpose, out = x*attn
    float* cLds = (float*)smem;              // [64][133] fp32 = 34048 B
    int rel0 = w*32 + kg*4;
    #pragma unroll
    for (int n = 0; n < 4; ++n) {
        int col = n*16 + lr;
        float bv = bias[bn + col];
        #pragma unroll
        for (int m = 0; m < 2; ++m) {
            #pragma unroll
            for (int j = 0; j < 4; ++j)
                cLds[col * 133 + rel0 + m*16 + j] = acc[m][n][j] + bv;
        }
    }
    __syncthreads();

    int d  = tid >> 2;                        // 0..63
    int po = (tid & 3) * 32;                  // pix offset within 128-tile
    int n_img = bm >> 12;
    int rem   = bm & 4095;
    size_t gb = (((size_t)(n_img * CC + bn + d)) << 12) + rem + po;
    const float* xr = x + gb;
    float* ow = out + gb;
    const float* cr = &cLds[d * 133 + po];
    #pragma unroll
    for (int j = 0; j < 32; j += 4) {
        float4 xv = *(const float4*)(xr + j);
        float4 r;
        r.x = xv.x * cr[j+0];
        r.y = xv.y * cr[j+1];
        r.z = xv.z * cr[j+2];
        r.w = xv.w * cr[j+3];
        *(float4*)(ow + j) = r;
    }
}

// ---------------------------------------------------------------------------
// K5 v9: two-phase dcn (R13 structure) + deep-MLP phase 2: points in batches
// of 3, all 12 corner uint4 loads register-buffered before FMA (~3x MLP).
__global__ void dcn_kernel(const __hip_bfloat16* __restrict__ xproj,
                           const __hip_bfloat16* __restrict__ off,
                           const __hip_bfloat16* __restrict__ mlog,
                           __hip_bfloat16* __restrict__ y) {
    __shared__ uint2 wLds[1152];    // 9216 B
    __shared__ int   oLds[1152];    // 4608 B
    int bid = blockIdx.x;
    int blk = (bid & 7) * 512 + (bid >> 3);
    int pix0 = blk * 8;
    int t = threadIdx.x;

    // ---- phase 1: softmax + folded weights, thread per (px, g) ----
    if (t < 128) {
        int px = t >> 4;
        int g  = t & 15;
        int pix = pix0 + px;
        int wo = pix & 63, ho = (pix >> 6) & 63;
        const __hip_bfloat16* mb = mlog + (size_t)pix * 144 + g * 9;
        float lg[9];
        float mx = -1e30f;
        #pragma unroll
        for (int p = 0; p < 9; ++p) { lg[p] = __bfloat162float(mb[p]); mx = fmaxf(mx, lg[p]); }
        float se = 0.f;
        #pragma unroll
        for (int p = 0; p < 9; ++p) { lg[p] = __expf(lg[p] - mx); se += lg[p]; }
        float rs = 1.0f / se;
        const unsigned* ob = (const unsigned*)(off + (size_t)pix * 288 + g * 18);
        #pragma unroll
        for (int p = 0; p < 9; ++p) {
            float ox, oy;
            bfu2(ob[p], ox, oy);
            float m = lg[p] * rs;
            int dx = p / 3 - 1;                 // kw-major
            int dy = p - (p / 3) * 3 - 1;
            float fx = (float)(wo + dx) + ox;
            float fy = (float)(ho + dy) + oy;
            float x0f = floorf(fx), y0f = floorf(fy);
            int x0 = (int)x0f, y0 = (int)y0f;
            int x1 = x0 + 1, y1 = y0 + 1;
            float wx1 = fx - x0f, wx0 = 1.0f - wx1;
            float wy1 = fy - y0f, wy0 = 1.0f - wy1;
            float vx0 = (x0 >= 0 && x0 < WW) ? 1.0f : 0.0f;
            float vx1 = (x1 >= 0 && x1 < WW) ? 1.0f : 0.0f;
            float vy0 = (y0 >= 0 && y0 < HH) ? 1.0f : 0.0f;
            float vy1 = (y1 >= 0 && y1 < HH) ? 1.0f : 0.0f;
            int x0c = min(max(x0, 0), WW - 1), x1c = min(max(x1, 0), WW - 1);
            int y0c = min(max(y0, 0), HH - 1), y1c = min(max(y1, 0), HH - 1);
            int tau = px * 144 + g * 9 + p;
            union { __half2 h2; unsigned u; } pa, pb;
            pa.h2 = __floats2half2_rn(m * wy0 * wx0 * vy0 * vx0,
                                      m * wy0 * wx1 * vy0 * vx1);
            pb.h2 = __floats2half2_rn(m * wy1 * wx0 * vy1 * vx0,
                                      m * wy1 * wx1 * vy1 * vx1);
            wLds[tau] = make_uint2(pa.u, pb.u);
            oLds[tau] = (y0c * WW + x0c) | ((x1c - x0c) << 12) | ((y1c - y0c) << 13);
        }
    }
    __syncthreads();

    // ---- phase 2: gather 8 channels per thread, 3-point register batching ----
    int px = t >> 5;
    int l  = t & 31;
    int g  = l >> 1;
    int ch = g * 16 + (l & 1) * 8;
    int pix = pix0 + px;
    int n = pix >> 12;
    const __hip_bfloat16* xb = xproj + ((size_t)n << 20) + ch;
    float a0=0,a1=0,a2=0,a3=0,a4=0,a5=0,a6=0,a7=0;
    const uint2* wp = &wLds[px * 144 + g * 9];
    const int*   op = &oLds[px * 144 + g * 9];

    #pragma unroll
    for (int p0 = 0; p0 < 9; p0 += 3) {
        uint4 ld[3][4];
        float ws[3][4];
        #pragma unroll
        for (int q = 0; q < 3; ++q) {
            int p = p0 + q;
            uint2 pw = wp[p];
            union { unsigned u; __half2 h2; } ua, ub;
            ua.u = pw.x; ub.u = pw.y;
            float2 fA = __half22float2(ua.h2);
            float2 fB = __half22float2(ub.h2);
            ws[q][0] = fA.x; ws[q][1] = fA.y; ws[q][2] = fB.x; ws[q][3] = fB.y;
            int pk = op[p];
            int base = (pk & 4095) << 8;
            int ddx  = ((pk >> 12) & 1) << 8;
            int ddy  = ((pk >> 13) & 1) << 14;
            ld[q][0] = *(const uint4*)(xb + base);
            ld[q][1] = *(const uint4*)(xb + base + ddx);
            ld[q][2] = *(const uint4*)(xb + base + ddy);
            ld[q][3] = *(const uint4*)(xb + base + ddy + ddx);
        }
        #pragma unroll
        for (int q = 0; q < 3; ++q) {
            #pragma unroll
            for (int cn = 0; cn < 4; ++cn) {
                float wv = ws[q][cn];
                uint4 u = ld[q][cn];
                float b0,b1,b2,b3,b4,b5,b6,b7;
                bfu2(u.x,b0,b1); bfu2(u.y,b2,b3); bfu2(u.z,b4,b5); bfu2(u.w,b6,b7);
                a0 += wv*b0; a1 += wv*b1; a2 += wv*b2; a3 += wv*b3;
                a4 += wv*b4; a5 += wv*b5; a6 += wv*b6; a7 += wv*b7;
            }
        }
    }
    union { __hip_bfloat16 h[8]; uint4 u; } ov;
    ov.h[0]=__float2bfloat16(a0); ov.h[1]=__float2bfloat16(a1);
    ov.h[2]=__float2bfloat16(a2); ov.h[3]=__float2bfloat16(a3);
    ov.h[4]=__float2bfloat16(a4); ov.h[5]=__float2bfloat16(a5);
    ov.h[6]=__float2bfloat16(a6); ov.h[7]=__float2bfloat16(a7);
    *(uint4*)(y + (size_t)pix * CC + ch) = ov.u;
}

// ---------------------------------------------------------------------------
extern "C" void kernel_launch(void* const* d_in, const int* in_sizes, int n_in,
                              void* d_out, int out_size, void* d_ws, size_t ws_size,
                              hipStream_t stream) {
    const float* x      = (const float*)d_in[0];
    const float* conv0w = (const float*)d_in[1];
    const float* conv0b = (const float*)d_in[2];
    const float* dww    = (const float*)d_in[3];
    const float* dwb    = (const float*)d_in[4];
    const float* lng    = (const float*)d_in[5];
    const float* lnb    = (const float*)d_in[6];
    const float* offw   = (const float*)d_in[7];
    const float* offb   = (const float*)d_in[8];
    const float* mskw   = (const float*)d_in[9];
    const float* mskb   = (const float*)d_in[10];
    const float* inw    = (const float*)d_in[11];
    const float* inb    = (const float*)d_in[12];
    const float* outpw  = (const float*)d_in[13];
    const float* outpb  = (const float*)d_in[14];
    const float* pww    = (const float*)d_in[15];
    const float* pwb    = (const float*)d_in[16];

    __hip_bfloat16* bfb = (__hip_bfloat16*)d_ws;
    __hip_bfloat16* inp_bf  = bfb;                   // 8,388,608 (y_bf alias)
    __hip_bfloat16* y_bf    = inp_bf;
    __hip_bfloat16* x1_bf   = bfb + 8388608;         // (xpj_bf alias)
    __hip_bfloat16* xpj_bf  = x1_bf;
    __hip_bfloat16* off_bf  = bfb + 16777216;        // 9,437,184
    __hip_bfloat16* msk_bf  = bfb + 26214400;        // 4,718,592
    __hip_bfloat16* bt_in   = bfb + 30932992;        // 256*256
    __hip_bfloat16* bt_om   = bt_in + 65536;         // 448*256 (off|msk concat)
    __hip_bfloat16* bt_wc   = bt_om + 114688;        // 256*256 (combined outp*pw)
    float* bcomb = (float*)(bt_wc + 65536);          // 256 floats
    float* bcat  = bcomb + 256;                      // 448 floats
    float* out = (float*)d_out;

    // 0. merged weight prep
    prep_kernel<<<963, 256, 0, stream>>>(inw, offw, mskw, outpw, pww, outpb, pwb,
                                         offb, mskb, bt_in, bt_om, bt_wc, bcomb, bcat);
    // 1. conv0 5x5 dw -> inp_bf (bf16 only)
    conv0_kernel<<<dim3(8, 16, BB), 256, 0, stream>>>(x, conv0w, conv0b, inp_bf);
    // 2. dw3x3 + LN + GELU -> x1_bf (packed-bf16 LDS halo)
    dwln_kernel<<<dim3(8, 64, BB), 256, 0, stream>>>(inp_bf, dww, dwb, lng, lnb, x1_bf);
    // 3. [offset | mask logits] = x1 @ bt_om + bcat -> off_bf / msk_bf (one GEMM)
    omgemm_kernel<<<dim3(7, 256), 256, 0, stream>>>(x1_bf, bt_om, bcat, off_bf, msk_bf);
    // 4. xproj = inp @ in_w + in_b -> bf16 (overwrites x1 region; x1 dead)
    mgemm_kernel<<<dim3(4, 256), 256, 0, stream>>>(inp_bf, bt_in, inb, xpj_bf, 256);
    // 5. DCN core (two-phase, 3-point register-batched gather) -> y_bf
    dcn_kernel<<<NPIX/8, 256, 0, stream>>>(xpj_bf, off_bf, msk_bf, y_bf);
    // 6. attn GEMM + fused finmul: out = x * (y @ Wc + bc)
    attn_fused_kernel<<<dim3(4, 256), 256, 0, stream>>>(y_bf, bt_wc, bcomb, x, out);
}